// Round 4
// baseline (1383.772 us; speedup 1.0000x reference)
//
#include <hip/hip_runtime.h>
#include <stdint.h>

typedef __bf16 bf16x8 __attribute__((ext_vector_type(8)));
typedef float f32x4 __attribute__((ext_vector_type(4)));

#define NSTEP 10
#define HALF_V 16777216u  /* 4096*4096: pair offset for (8192,4096) uniforms */
#define HALF_H 262144u    /* 4096*64:   pair offset for (8192,64)   uniforms */
#define XPS 516           /* Xp row stride (floats); 516*4 % 128B => 2-way-free banks */

struct TFKeys {
  uint32_t kh0_0, kh0_1;                 // fold_in(key(42), 0) — initial h sample
  uint32_t kv0[NSTEP], kv1[NSTEP];       // per-step v keys
  uint32_t khs0[NSTEP], khs1[NSTEP];     // per-step h keys
};

__host__ __device__ __forceinline__ uint32_t rotl_(uint32_t x, uint32_t r) {
#ifdef __HIP_DEVICE_COMPILE__
  return __builtin_amdgcn_alignbit(x, x, 32u - r);   // 1-instr rotate
#else
  return (x << r) | (x >> (32u - r));
#endif
}

#define TF_ROUND(r) { x0 += x1; x1 = rotl_(x1, (r)); x1 ^= x0; }

__host__ __device__ __forceinline__ void tf2x32(uint32_t k0, uint32_t k1,
    uint32_t x0, uint32_t x1, uint32_t& o0, uint32_t& o1) {
  const uint32_t k2 = k0 ^ k1 ^ 0x1BD11BDAu;
  x0 += k0; x1 += k1;
  TF_ROUND(13) TF_ROUND(15) TF_ROUND(26) TF_ROUND(6)
  x0 += k1; x1 += k2 + 1u;
  TF_ROUND(17) TF_ROUND(29) TF_ROUND(16) TF_ROUND(24)
  x0 += k2; x1 += k0 + 2u;
  TF_ROUND(13) TF_ROUND(15) TF_ROUND(26) TF_ROUND(6)
  x0 += k0; x1 += k1 + 3u;
  TF_ROUND(17) TF_ROUND(29) TF_ROUND(16) TF_ROUND(24)
  x0 += k1; x1 += k2 + 4u;
  TF_ROUND(13) TF_ROUND(15) TF_ROUND(26) TF_ROUND(6)
  x0 += k2; x1 += k0 + 5u;
  o0 = x0; o1 = x1;
}

__device__ __forceinline__ float tf_uniform(uint32_t bits) {
  return __uint_as_float((bits >> 9) | 0x3F800000u) - 1.0f;   // [0,1) like JAX
}

__device__ __forceinline__ float softplusf_(float x) {
  return fmaxf(x, 0.0f) + log1pf(__expf(-fabsf(x)));
}

// sigmoid(x) > u  <=>  u*e^{-x} + u < 1   (saves v_rcp + v_add per sample)
__device__ __forceinline__ bool sig_gt(float x, float u) {
  return fmaf(u, __expf(-x), u) < 1.0f;
}

__device__ __forceinline__ unsigned short f2bf(float f) {
  uint32_t u = __float_as_uint(f);
  uint32_t r = (u + 0x7FFFu + ((u >> 16) & 1u)) >> 16;  // RNE
  return (unsigned short)r;
}

__device__ __forceinline__ bf16x8 as8(uint4 u) { return __builtin_bit_cast(bf16x8, u); }

// ---- prep: w (f32 [4096,64]) -> split bf16 (hi+lo) row-major + transposed ----
__global__ void prep_w(const float* __restrict__ w,
                       unsigned short* __restrict__ w_hi, unsigned short* __restrict__ w_lo,
                       unsigned short* __restrict__ wt_hi, unsigned short* __restrict__ wt_lo) {
  int t = blockIdx.x * 256 + threadIdx.x;   // 262144 total
  int i = t >> 6, j = t & 63;
  float f = w[t];
  unsigned short hi = f2bf(f);
  float fh = __uint_as_float((uint32_t)hi << 16);
  unsigned short lo = f2bf(f - fh);
  w_hi[t] = hi;             w_lo[t] = lo;
  wt_hi[j * 4096 + i] = hi; wt_lo[j * 4096 + i] = lo;
}

// ---- h tail: 512 ciphers/block (1 per thread): p = wave, j = lane ----
// MODE 0: acc_fe -= softplus, sample h   (X0 phase)
// MODE 1: sample h only                   (mid steps)
// MODE 2: acc_fe += softplus, no sample   (last step)
template<int MODE>
__device__ __forceinline__ void h_tail(int p, int j, int b0, uint32_t k0, uint32_t k1,
    float& acc_fe, const float* Xp, const float* hb_lds, unsigned short (*h_lds)[72]) {
  const float* xl = Xp + (2 * p) * XPS + j;
  const float* xh = Xp + (2 * p + 1) * XPS + j;
  float s0 = 0.f, s1 = 0.f;
  #pragma unroll
  for (int w = 0; w < 8; ++w) { s0 += xl[w * 64]; s1 += xh[w * 64]; }
  float hbv = hb_lds[j];
  float xlo = s0 + hbv, xhi = s1 + hbv;
  if (MODE == 2) { acc_fe += softplusf_(xlo) + softplusf_(xhi); return; }
  if (MODE == 0) acc_fe -= softplusf_(xlo) + softplusf_(xhi);
  uint32_t e0 = (uint32_t)(b0 + p) * 64u + (uint32_t)j;
  uint32_t o0, o1;
  tf2x32(k0, k1, e0, e0 + HALF_H, o0, o1);
  h_lds[2 * p][j]     = sig_gt(xlo, tf_uniform(o0)) ? (unsigned short)0x3F80 : (unsigned short)0;
  h_lds[2 * p + 1][j] = sig_gt(xhi, tf_uniform(o1)) ? (unsigned short)0x3F80 : (unsigned short)0;
}

// ---- one Gibbs step. MFMA row m = 2p + s: pair p = m>>1 (phys rows b0+p /
// 4096+b0+p), so each lane's q-quad {4lg..4lg+3} = pairs {2lg, 2lg+1} complete
// -> one cipher per 2 samples, both outputs consumed in-lane. ----
template<bool LAST>
__device__ __forceinline__ void gibbs_step(
    int wv, int l, int lg, int lr, int b0, int colbase,
    uint32_t kv0, uint32_t kv1, uint32_t kh0, uint32_t kh1,
    const unsigned short* __restrict__ w_hi, const unsigned short* __restrict__ w_lo,
    const unsigned short* __restrict__ wt_hi, const unsigned short* __restrict__ wt_lo,
    const float* __restrict__ vb,
    unsigned short (*v_lds)[16][72], unsigned short (*h_lds)[72],
    float* Xp, const float* hb_lds, float& acc_fe)
{
  bf16x8 ha0 = as8(*(const uint4*)&h_lds[lr][lg * 8]);
  bf16x8 ha1 = as8(*(const uint4*)&h_lds[lr][32 + lg * 8]);
  f32x4 accx[4];
  #pragma unroll
  for (int ct = 0; ct < 4; ++ct) accx[ct] = f32x4{0.f, 0.f, 0.f, 0.f};

  #pragma unroll 1
  for (int sc = 0; sc < 8; ++sc) {
    const int base = colbase + sc * 64;
    // ---- v-phase: 4 tiles of 16 cols ----
    #pragma unroll
    for (int t = 0; t < 4; ++t) {
      const int ig = base + t * 16 + lr;
      const uint4* wh = (const uint4*)(w_hi + (size_t)ig * 64);
      const uint4* wl = (const uint4*)(w_lo + (size_t)ig * 64);
      uint4 bh0 = wh[lg], bh1 = wh[4 + lg];
      uint4 bl0 = wl[lg], bl1 = wl[4 + lg];
      const float vbv = vb[ig];
      // 2 ciphers (pairs 2lg, 2lg+1) — independent of MFMA, overlaps load latency
      uint32_t c0 = (uint32_t)(b0 + 2 * lg) * 4096u + (uint32_t)ig;
      uint32_t oA0, oA1, oB0, oB1;
      tf2x32(kv0, kv1, c0, c0 + HALF_V, oA0, oA1);
      tf2x32(kv0, kv1, c0 + 4096u, c0 + 4096u + HALF_V, oB0, oB1);
      f32x4 a = {vbv, vbv, vbv, vbv};                 // vb folded into C-init
      a = __builtin_amdgcn_mfma_f32_16x16x32_bf16(ha0, as8(bh0), a, 0, 0, 0);
      a = __builtin_amdgcn_mfma_f32_16x16x32_bf16(ha1, as8(bh1), a, 0, 0, 0);
      a = __builtin_amdgcn_mfma_f32_16x16x32_bf16(ha0, as8(bl0), a, 0, 0, 0);
      a = __builtin_amdgcn_mfma_f32_16x16x32_bf16(ha1, as8(bl1), a, 0, 0, 0);
      const uint32_t bits[4] = {oA0, oA1, oB0, oB1};  // q-unroll => static idx
      #pragma unroll
      for (int q = 0; q < 4; ++q) {
        bool s = sig_gt(a[q], tf_uniform(bits[q]));
        v_lds[wv][4 * lg + q][t * 16 + lr] = s ? (unsigned short)0x3F80 : (unsigned short)0;
        if (LAST) acc_fe += s ? vbv : 0.0f;           // + v.vb (last step only)
      }
    }
    // ---- h-phase partial: X += Vchunk @ W (hi + lo) ----
    #pragma unroll
    for (int ks = 0; ks < 2; ++ks) {
      const int kg = base + ks * 32;
      bf16x8 A0 = as8(*(const uint4*)&v_lds[wv][lr][ks * 32 + lg * 8]);
      #pragma unroll
      for (int ct = 0; ct < 4; ++ct) {
        size_t wo = (size_t)(ct * 16 + lr) * 4096 + kg + lg * 8;
        accx[ct] = __builtin_amdgcn_mfma_f32_16x16x32_bf16(A0, as8(*(const uint4*)(wt_hi + wo)), accx[ct], 0, 0, 0);
        accx[ct] = __builtin_amdgcn_mfma_f32_16x16x32_bf16(A0, as8(*(const uint4*)(wt_lo + wo)), accx[ct], 0, 0, 0);
      }
    }
  }
  #pragma unroll
  for (int ct = 0; ct < 4; ++ct)
    #pragma unroll
    for (int q = 0; q < 4; ++q)
      Xp[(4 * lg + q) * XPS + wv * 64 + ct * 16 + lr] = accx[ct][q];
  __syncthreads();
  if (LAST) h_tail<2>(wv, l, b0, 0u, 0u, acc_fe, Xp, hb_lds, h_lds);
  else      h_tail<1>(wv, l, b0, kh0, kh1, acc_fe, Xp, hb_lds, h_lds);
  __syncthreads();
}

// ---- fused CD-10 chain + free energy; 16 rows (8 pairs) / block; 512 blocks ----
__global__ __launch_bounds__(512, 4)
void rbm_chain(const float* __restrict__ inputs, const float* __restrict__ vb,
               const float* __restrict__ hb,
               const unsigned short* __restrict__ w_hi, const unsigned short* __restrict__ w_lo,
               const unsigned short* __restrict__ wt_hi, const unsigned short* __restrict__ wt_lo,
               float* __restrict__ partial, TFKeys K) {
  __shared__ unsigned short v_lds[8][16][72];  // per-wave 64-col sub-chunk, rows = MFMA rows
  __shared__ unsigned short h_lds[16][72];
  __shared__ float Xp[16 * XPS];               // [mfma_row][wave*64 + j]
  __shared__ float hb_lds[64];
  __shared__ float red[8];

  const int tid = threadIdx.x;
  const int wv  = tid >> 6;    // wave 0..7
  const int l   = tid & 63;
  const int lg  = l >> 4;      // 0..3
  const int lr  = l & 15;
  const int b0  = blockIdx.x * 8;   // low-row base (pairs b0..b0+7 with +4096)
  const int colbase = wv * 512;

  if (tid < 64) hb_lds[tid] = hb[tid];

  float acc_fe = 0.0f;

  // ================= X0 = inputs @ w : bias_in, cond_in, sample h0 ==========
  {
    f32x4 accx[4];
    #pragma unroll
    for (int ct = 0; ct < 4; ++ct) accx[ct] = f32x4{0.f, 0.f, 0.f, 0.f};
    #pragma unroll 1
    for (int sc = 0; sc < 8; ++sc) {
      const int base = colbase + sc * 64;
      #pragma unroll
      for (int u = 0; u < 4; ++u) {
        int idx = u * 64 + l;            // 0..255
        int m = idx >> 4, f4 = idx & 15; // MFMA row, float4 index
        int phys = b0 + (m >> 1) + ((m & 1) << 12);   // interleaved pair mapping
        float4 x  = *(const float4*)(inputs + (size_t)phys * 4096 + base + f4 * 4);
        float4 vv = *(const float4*)(vb + base + f4 * 4);
        acc_fe -= x.x * vv.x + x.y * vv.y + x.z * vv.z + x.w * vv.w;
        ushort4 h4;
        h4.x = f2bf(x.x); h4.y = f2bf(x.y); h4.z = f2bf(x.z); h4.w = f2bf(x.w);
        *(ushort4*)&v_lds[wv][m][f4 * 4] = h4;
      }
      #pragma unroll
      for (int ks = 0; ks < 2; ++ks) {
        const int kg = base + ks * 32;
        bf16x8 A0 = as8(*(const uint4*)&v_lds[wv][lr][ks * 32 + lg * 8]);
        #pragma unroll
        for (int ct = 0; ct < 4; ++ct) {
          size_t wo = (size_t)(ct * 16 + lr) * 4096 + kg + lg * 8;
          accx[ct] = __builtin_amdgcn_mfma_f32_16x16x32_bf16(A0, as8(*(const uint4*)(wt_hi + wo)), accx[ct], 0, 0, 0);
          accx[ct] = __builtin_amdgcn_mfma_f32_16x16x32_bf16(A0, as8(*(const uint4*)(wt_lo + wo)), accx[ct], 0, 0, 0);
        }
      }
    }
    #pragma unroll
    for (int ct = 0; ct < 4; ++ct)
      #pragma unroll
      for (int q = 0; q < 4; ++q)
        Xp[(4 * lg + q) * XPS + wv * 64 + ct * 16 + lr] = accx[ct][q];
    __syncthreads();
    h_tail<0>(wv, l, b0, K.kh0_0, K.kh0_1, acc_fe, Xp, hb_lds, h_lds);
    __syncthreads();
  }

  // ======================= 10 Gibbs steps ===================================
  #pragma unroll 1
  for (int step = 0; step < NSTEP - 1; ++step)
    gibbs_step<false>(wv, l, lg, lr, b0, colbase,
                      K.kv0[step], K.kv1[step], K.khs0[step], K.khs1[step],
                      w_hi, w_lo, wt_hi, wt_lo, vb, v_lds, h_lds, Xp, hb_lds, acc_fe);
  gibbs_step<true>(wv, l, lg, lr, b0, colbase,
                   K.kv0[NSTEP - 1], K.kv1[NSTEP - 1], 0u, 0u,
                   w_hi, w_lo, wt_hi, wt_lo, vb, v_lds, h_lds, Xp, hb_lds, acc_fe);

  // ---- block reduction ----
  float v = acc_fe;
  #pragma unroll
  for (int off = 32; off; off >>= 1) v += __shfl_down(v, off);
  if (l == 0) red[wv] = v;
  __syncthreads();
  if (tid == 0) {
    float s = 0.f;
    #pragma unroll
    for (int i = 0; i < 8; ++i) s += red[i];
    partial[blockIdx.x] = s;
  }
}

__global__ void finish_reduce(const float* __restrict__ partial, float* __restrict__ out) {
  __shared__ float r[8];
  float v = partial[threadIdx.x];   // 512 threads
  #pragma unroll
  for (int off = 32; off; off >>= 1) v += __shfl_down(v, off);
  if ((threadIdx.x & 63) == 0) r[threadIdx.x >> 6] = v;
  __syncthreads();
  if (threadIdx.x == 0) {
    float s = 0.f;
    #pragma unroll
    for (int i = 0; i < 8; ++i) s += r[i];
    out[0] = s;
  }
}

extern "C" void kernel_launch(void* const* d_in, const int* in_sizes, int n_in,
                              void* d_out, int out_size, void* d_ws, size_t ws_size,
                              hipStream_t stream) {
  const float* inputs = (const float*)d_in[0];
  const float* w      = (const float*)d_in[1];
  const float* vb     = (const float*)d_in[2];
  const float* hb     = (const float*)d_in[3];
  float* out = (float*)d_out;

  unsigned short* w_hi  = (unsigned short*)d_ws;                          // 512 KB
  unsigned short* w_lo  = (unsigned short*)((char*)d_ws + (512u << 10));  // 512 KB
  unsigned short* wt_hi = (unsigned short*)((char*)d_ws + (1024u << 10)); // 512 KB
  unsigned short* wt_lo = (unsigned short*)((char*)d_ws + (1536u << 10)); // 512 KB
  float* partial        = (float*)((char*)d_ws + (2048u << 10));          // 2 KB

  // ---- JAX threefry key schedule on host (pure arithmetic, capture-safe) ----
  TFKeys K;
  uint32_t kc0, kc1;
  tf2x32(0u, 42u, 0u, 0u, K.kh0_0, K.kh0_1);   // fold_in(key(42), 0)
  tf2x32(0u, 42u, 0u, 1u, kc0, kc1);           // fold_in(key(42), 1)
  // split(kchain, 10): counts = iota(20), cipher pairs (i, 10+i)
  uint32_t A[NSTEP], B[NSTEP], flat[2 * NSTEP];
  for (int i = 0; i < NSTEP; ++i) tf2x32(kc0, kc1, (uint32_t)i, (uint32_t)(NSTEP + i), A[i], B[i]);
  for (int i = 0; i < NSTEP; ++i) { flat[i] = A[i]; flat[NSTEP + i] = B[i]; }
  for (int t = 0; t < NSTEP; ++t) {
    uint32_t key0 = flat[2 * t], key1 = flat[2 * t + 1];
    // split(keys[t], 2): counts = iota(4), cipher pairs (0,2) and (1,3)
    uint32_t C0, D0, C1, D1;
    tf2x32(key0, key1, 0u, 2u, C0, D0);
    tf2x32(key0, key1, 1u, 3u, C1, D1);
    K.kv0[t] = C0; K.kv1[t] = C1;    // kv = first row of reshaped (2,2)
    K.khs0[t] = D0; K.khs1[t] = D1;  // kh = second row
  }

  prep_w<<<1024, 256, 0, stream>>>(w, w_hi, w_lo, wt_hi, wt_lo);
  rbm_chain<<<512, 512, 0, stream>>>(inputs, vb, hb, w_hi, w_lo, wt_hi, wt_lo, partial, K);
  finish_reduce<<<1, 512, 0, stream>>>(partial, out);
}

// Round 5
// 812.666 us; speedup vs baseline: 1.7028x; 1.7028x over previous
//
#include <hip/hip_runtime.h>
#include <stdint.h>

typedef __bf16 bf16x8 __attribute__((ext_vector_type(8)));
typedef float f32x4 __attribute__((ext_vector_type(4)));

#define NSTEP 10
#define HALF_V 16777216u  /* 4096*4096: pair offset for (8192,4096) uniforms */
#define HALF_H 262144u    /* 4096*64:   pair offset for (8192,64)   uniforms */

struct TFKeys {
  uint32_t kh0_0, kh0_1;                 // fold_in(key(42), 0) — initial h sample
  uint32_t kv0[NSTEP], kv1[NSTEP];       // per-step v keys
  uint32_t khs0[NSTEP], khs1[NSTEP];     // per-step h keys
};

__host__ __device__ __forceinline__ uint32_t rotl_(uint32_t x, uint32_t r) {
#ifdef __HIP_DEVICE_COMPILE__
  return __builtin_amdgcn_alignbit(x, x, 32u - r);   // 1-instr rotate
#else
  return (x << r) | (x >> (32u - r));
#endif
}

#define TF_ROUND(r) { x0 += x1; x1 = rotl_(x1, (r)); x1 ^= x0; }

__host__ __device__ __forceinline__ void tf2x32(uint32_t k0, uint32_t k1,
    uint32_t x0, uint32_t x1, uint32_t& o0, uint32_t& o1) {
  const uint32_t k2 = k0 ^ k1 ^ 0x1BD11BDAu;
  x0 += k0; x1 += k1;
  TF_ROUND(13) TF_ROUND(15) TF_ROUND(26) TF_ROUND(6)
  x0 += k1; x1 += k2 + 1u;
  TF_ROUND(17) TF_ROUND(29) TF_ROUND(16) TF_ROUND(24)
  x0 += k2; x1 += k0 + 2u;
  TF_ROUND(13) TF_ROUND(15) TF_ROUND(26) TF_ROUND(6)
  x0 += k0; x1 += k1 + 3u;
  TF_ROUND(17) TF_ROUND(29) TF_ROUND(16) TF_ROUND(24)
  x0 += k1; x1 += k2 + 4u;
  TF_ROUND(13) TF_ROUND(15) TF_ROUND(26) TF_ROUND(6)
  x0 += k2; x1 += k0 + 5u;
  o0 = x0; o1 = x1;
}

__device__ __forceinline__ float tf_uniform(uint32_t bits) {
  return __uint_as_float((bits >> 9) | 0x3F800000u) - 1.0f;   // [0,1) like JAX
}

__device__ __forceinline__ float softplusf_(float x) {
  return fmaxf(x, 0.0f) + log1pf(__expf(-fabsf(x)));
}

// sigmoid(x) > u  <=>  u*e^{-x} + u < 1   (saves v_rcp + v_add per sample)
__device__ __forceinline__ bool sig_gt(float x, float u) {
  return fmaf(u, __expf(-x), u) < 1.0f;
}

__device__ __forceinline__ unsigned short f2bf(float f) {
  uint32_t u = __float_as_uint(f);
  uint32_t r = (u + 0x7FFFu + ((u >> 16) & 1u)) >> 16;  // RNE
  return (unsigned short)r;
}

__device__ __forceinline__ bf16x8 as8(uint4 u) { return __builtin_bit_cast(bf16x8, u); }

// ---- prep: w (f32 [4096,64]) -> split bf16 (hi+lo) row-major + transposed ----
__global__ void prep_w(const float* __restrict__ w,
                       unsigned short* __restrict__ w_hi, unsigned short* __restrict__ w_lo,
                       unsigned short* __restrict__ wt_hi, unsigned short* __restrict__ wt_lo) {
  int t = blockIdx.x * 256 + threadIdx.x;   // 262144 total
  int i = t >> 6, j = t & 63;
  float f = w[t];
  unsigned short hi = f2bf(f);
  float fh = __uint_as_float((uint32_t)hi << 16);
  unsigned short lo = f2bf(f - fh);
  w_hi[t] = hi;             w_lo[t] = lo;
  wt_hi[j * 4096 + i] = hi; wt_lo[j * 4096 + i] = lo;
}

// ---- h tail: 1024 ciphers/block (1 per thread): p = tid>>6 (=wave), j = lane ----
// MODE 0: acc_fe -= softplus, sample h   (X0 phase)
// MODE 1: sample h only                   (mid steps)
// MODE 2: acc_fe += softplus, no sample   (last step)
template<int MODE>
__device__ __forceinline__ void h_tail(int p, int j, int b0, uint32_t k0, uint32_t k1,
    float& acc_fe, const float (*Xp)[32][66], const float* hb_lds,
    unsigned short (*h_lds)[72]) {
  float s0 = 0.f, s1 = 0.f;
  #pragma unroll
  for (int s = 0; s < 8; ++s) { s0 += Xp[s][p][j]; s1 += Xp[s][p + 16][j]; }
  float hbv = hb_lds[j];
  float xlo = s0 + hbv, xhi = s1 + hbv;
  if (MODE == 2) { acc_fe += softplusf_(xlo) + softplusf_(xhi); return; }
  if (MODE == 0) acc_fe -= softplusf_(xlo) + softplusf_(xhi);
  uint32_t e0 = (uint32_t)(b0 + p) * 64u + (uint32_t)j;
  uint32_t o0, o1;
  tf2x32(k0, k1, e0, e0 + HALF_H, o0, o1);
  h_lds[p][j]      = sig_gt(xlo, tf_uniform(o0)) ? (unsigned short)0x3F80 : (unsigned short)0;
  h_lds[16 + p][j] = sig_gt(xhi, tf_uniform(o1)) ? (unsigned short)0x3F80 : (unsigned short)0;
}

// ---- deterministic 16->8 slot exchange + tail + barriers ----
template<int MODE>
__device__ __forceinline__ void exchange_and_tail(
    int wv, int l, int lg, int lr, int b0, uint32_t k0, uint32_t k1,
    const f32x4 (*accx)[4], float (*Xp)[32][66], const float* hb_lds,
    unsigned short (*h_lds)[72], float& acc_fe, int tid) {
  const int slot = wv & 7;
  if (wv >= 8) {
    #pragma unroll
    for (int rt = 0; rt < 2; ++rt)
      #pragma unroll
      for (int ct = 0; ct < 4; ++ct)
        #pragma unroll
        for (int q = 0; q < 4; ++q)
          Xp[slot][rt * 16 + lg * 4 + q][ct * 16 + lr] = accx[rt][ct][q];
  }
  __syncthreads();
  if (wv < 8) {
    #pragma unroll
    for (int rt = 0; rt < 2; ++rt)
      #pragma unroll
      for (int ct = 0; ct < 4; ++ct)
        #pragma unroll
        for (int q = 0; q < 4; ++q)
          Xp[slot][rt * 16 + lg * 4 + q][ct * 16 + lr] += accx[rt][ct][q];
  }
  __syncthreads();
  h_tail<MODE>(wv, l, b0, k0, k1, acc_fe, (const float (*)[32][66])Xp, hb_lds, h_lds);
  __syncthreads();
}

// ---- one Gibbs step: wave owns 32 rows x 256-col slice, R3-level ILP ----
template<bool LAST>
__device__ __forceinline__ void gibbs_step(
    int wv, int l, int lg, int lr, int b0, int colbase,
    uint32_t kv0, uint32_t kv1, uint32_t kh0, uint32_t kh1,
    const unsigned short* __restrict__ w_hi, const unsigned short* __restrict__ w_lo,
    const unsigned short* __restrict__ wt_hi, const unsigned short* __restrict__ wt_lo,
    const float* vb_lds, unsigned short (*v_lds)[32][72], unsigned short (*h_lds)[72],
    float (*Xp)[32][66], const float* hb_lds, float& acc_fe, int tid)
{
  bf16x8 ha00 = as8(*(const uint4*)&h_lds[lr][lg * 8]);
  bf16x8 ha01 = as8(*(const uint4*)&h_lds[lr][32 + lg * 8]);
  bf16x8 ha10 = as8(*(const uint4*)&h_lds[16 + lr][lg * 8]);
  bf16x8 ha11 = as8(*(const uint4*)&h_lds[16 + lr][32 + lg * 8]);

  f32x4 accx[2][4];
  #pragma unroll
  for (int rt = 0; rt < 2; ++rt)
    #pragma unroll
    for (int ct = 0; ct < 4; ++ct) accx[rt][ct] = f32x4{0.f, 0.f, 0.f, 0.f};

  #pragma unroll 1
  for (int sc = 0; sc < 4; ++sc) {
    const int base = colbase + sc * 64;
    // ---- v-phase: 4 tiles of 16 cols; 4 ciphers + 8 MFMAs in flight per tile ----
    #pragma unroll
    for (int t = 0; t < 4; ++t) {
      const int ig = base + t * 16 + lr;
      const uint4* wh = (const uint4*)(w_hi + (size_t)ig * 64);
      const uint4* wl = (const uint4*)(w_lo + (size_t)ig * 64);
      uint4 bh0 = wh[lg], bh1 = wh[4 + lg];
      uint4 bl0 = wl[lg], bl1 = wl[4 + lg];
      const float vbv = vb_lds[ig];
      uint32_t oL[4], oH[4];
      #pragma unroll
      for (int q = 0; q < 4; ++q) {
        uint32_t e0 = (uint32_t)(b0 + lg * 4 + q) * 4096u + (uint32_t)ig;
        tf2x32(kv0, kv1, e0, e0 + HALF_V, oL[q], oH[q]);
      }
      f32x4 a0 = {vbv, vbv, vbv, vbv};             // vb folded into C-init
      f32x4 a1 = {vbv, vbv, vbv, vbv};
      a0 = __builtin_amdgcn_mfma_f32_16x16x32_bf16(ha00, as8(bh0), a0, 0, 0, 0);
      a0 = __builtin_amdgcn_mfma_f32_16x16x32_bf16(ha01, as8(bh1), a0, 0, 0, 0);
      a0 = __builtin_amdgcn_mfma_f32_16x16x32_bf16(ha00, as8(bl0), a0, 0, 0, 0);
      a0 = __builtin_amdgcn_mfma_f32_16x16x32_bf16(ha01, as8(bl1), a0, 0, 0, 0);
      a1 = __builtin_amdgcn_mfma_f32_16x16x32_bf16(ha10, as8(bh0), a1, 0, 0, 0);
      a1 = __builtin_amdgcn_mfma_f32_16x16x32_bf16(ha11, as8(bh1), a1, 0, 0, 0);
      a1 = __builtin_amdgcn_mfma_f32_16x16x32_bf16(ha10, as8(bl0), a1, 0, 0, 0);
      a1 = __builtin_amdgcn_mfma_f32_16x16x32_bf16(ha11, as8(bl1), a1, 0, 0, 0);
      #pragma unroll
      for (int q = 0; q < 4; ++q) {
        const int rit = lg * 4 + q;
        bool s0 = sig_gt(a0[q], tf_uniform(oL[q]));
        bool s1 = sig_gt(a1[q], tf_uniform(oH[q]));
        v_lds[wv][rit][t * 16 + lr]      = s0 ? (unsigned short)0x3F80 : (unsigned short)0;
        v_lds[wv][16 + rit][t * 16 + lr] = s1 ? (unsigned short)0x3F80 : (unsigned short)0;
        if (LAST) acc_fe += (s0 ? vbv : 0.0f) + (s1 ? vbv : 0.0f);  // + v.vb
      }
    }
    // ---- h-phase partial: X += Vchunk @ W (hi + lo, both row-tiles) ----
    #pragma unroll
    for (int ks = 0; ks < 2; ++ks) {
      bf16x8 A0 = as8(*(const uint4*)&v_lds[wv][lr][ks * 32 + lg * 8]);
      bf16x8 A1 = as8(*(const uint4*)&v_lds[wv][16 + lr][ks * 32 + lg * 8]);
      #pragma unroll
      for (int ct = 0; ct < 4; ++ct) {
        size_t wo = (size_t)(ct * 16 + lr) * 4096 + base + ks * 32 + lg * 8;
        bf16x8 bh = as8(*(const uint4*)(wt_hi + wo));
        bf16x8 bl = as8(*(const uint4*)(wt_lo + wo));
        accx[0][ct] = __builtin_amdgcn_mfma_f32_16x16x32_bf16(A0, bh, accx[0][ct], 0, 0, 0);
        accx[0][ct] = __builtin_amdgcn_mfma_f32_16x16x32_bf16(A0, bl, accx[0][ct], 0, 0, 0);
        accx[1][ct] = __builtin_amdgcn_mfma_f32_16x16x32_bf16(A1, bh, accx[1][ct], 0, 0, 0);
        accx[1][ct] = __builtin_amdgcn_mfma_f32_16x16x32_bf16(A1, bl, accx[1][ct], 0, 0, 0);
      }
    }
  }
  if (LAST)
    exchange_and_tail<2>(wv, l, lg, lr, b0, 0u, 0u,
                         (const f32x4 (*)[4])accx, Xp, hb_lds, h_lds, acc_fe, tid);
  else
    exchange_and_tail<1>(wv, l, lg, lr, b0, kh0, kh1,
                         (const f32x4 (*)[4])accx, Xp, hb_lds, h_lds, acc_fe, tid);
}

// ---- fused CD-10 chain + free energy; 32 rows/block; 1024 threads (16 waves) ----
__global__ __launch_bounds__(1024, 4)
void rbm_chain(const float* __restrict__ inputs, const float* __restrict__ vb,
               const float* __restrict__ hb,
               const unsigned short* __restrict__ w_hi, const unsigned short* __restrict__ w_lo,
               const unsigned short* __restrict__ wt_hi, const unsigned short* __restrict__ wt_lo,
               float* __restrict__ partial, TFKeys K) {
  __shared__ __align__(16) unsigned short v_lds[16][32][72];  // per-wave 64-col chunk (73.7KB)
  __shared__ __align__(16) unsigned short h_lds[32][72];      // 4.6KB
  __shared__ float Xp[8][32][66];                             // 8 exchange slots (67.6KB)
  __shared__ float vb_lds[4096];                              // 16KB
  __shared__ float hb_lds[64];
  __shared__ float red[16];

  const int tid = threadIdx.x;
  const int wv  = tid >> 6;    // wave 0..15
  const int l   = tid & 63;
  const int lg  = l >> 4;      // 0..3
  const int lr  = l & 15;
  const int b0  = blockIdx.x * 16;   // low-row base (pairs b0+p / 4096+b0+p)
  const int colbase = wv * 256;

  if (tid < 1024) ((float4*)vb_lds)[tid] = ((const float4*)vb)[tid];
  if (tid < 64) hb_lds[tid] = hb[tid];
  __syncthreads();

  float acc_fe = 0.0f;

  // ================= X0 = inputs @ w : bias_in, cond_in, sample h0 ==========
  {
    f32x4 accx[2][4];
    #pragma unroll
    for (int rt = 0; rt < 2; ++rt)
      #pragma unroll
      for (int ct = 0; ct < 4; ++ct) accx[rt][ct] = f32x4{0.f, 0.f, 0.f, 0.f};
    #pragma unroll 1
    for (int sc = 0; sc < 4; ++sc) {
      const int base = colbase + sc * 64;
      // stage 32 rows x 64 cols -> bf16; accumulate -inputs.vb
      #pragma unroll
      for (int u = 0; u < 8; ++u) {
        int idx = u * 64 + l;            // 0..511
        int row = idx >> 4, f4 = idx & 15;
        int phys = (row < 16) ? (b0 + row) : (4096 + b0 + row - 16);
        int gcol = base + f4 * 4;
        float4 x  = *(const float4*)(inputs + (size_t)phys * 4096 + gcol);
        float4 vv = *(const float4*)(vb_lds + gcol);
        acc_fe -= x.x * vv.x + x.y * vv.y + x.z * vv.z + x.w * vv.w;
        ushort4 h4;
        h4.x = f2bf(x.x); h4.y = f2bf(x.y); h4.z = f2bf(x.z); h4.w = f2bf(x.w);
        *(ushort4*)&v_lds[wv][row][f4 * 4] = h4;
      }
      #pragma unroll
      for (int ks = 0; ks < 2; ++ks) {
        bf16x8 A0 = as8(*(const uint4*)&v_lds[wv][lr][ks * 32 + lg * 8]);
        bf16x8 A1 = as8(*(const uint4*)&v_lds[wv][16 + lr][ks * 32 + lg * 8]);
        #pragma unroll
        for (int ct = 0; ct < 4; ++ct) {
          size_t wo = (size_t)(ct * 16 + lr) * 4096 + base + ks * 32 + lg * 8;
          bf16x8 bh = as8(*(const uint4*)(wt_hi + wo));
          bf16x8 bl = as8(*(const uint4*)(wt_lo + wo));
          accx[0][ct] = __builtin_amdgcn_mfma_f32_16x16x32_bf16(A0, bh, accx[0][ct], 0, 0, 0);
          accx[0][ct] = __builtin_amdgcn_mfma_f32_16x16x32_bf16(A0, bl, accx[0][ct], 0, 0, 0);
          accx[1][ct] = __builtin_amdgcn_mfma_f32_16x16x32_bf16(A1, bh, accx[1][ct], 0, 0, 0);
          accx[1][ct] = __builtin_amdgcn_mfma_f32_16x16x32_bf16(A1, bl, accx[1][ct], 0, 0, 0);
        }
      }
    }
    exchange_and_tail<0>(wv, l, lg, lr, b0, K.kh0_0, K.kh0_1,
                         (const f32x4 (*)[4])accx, Xp, hb_lds, h_lds, acc_fe, tid);
  }

  // ======================= 10 Gibbs steps ===================================
  #pragma unroll 1
  for (int step = 0; step < NSTEP - 1; ++step)
    gibbs_step<false>(wv, l, lg, lr, b0, colbase,
                      K.kv0[step], K.kv1[step], K.khs0[step], K.khs1[step],
                      w_hi, w_lo, wt_hi, wt_lo, vb_lds, v_lds, h_lds, Xp, hb_lds, acc_fe, tid);
  gibbs_step<true>(wv, l, lg, lr, b0, colbase,
                   K.kv0[NSTEP - 1], K.kv1[NSTEP - 1], 0u, 0u,
                   w_hi, w_lo, wt_hi, wt_lo, vb_lds, v_lds, h_lds, Xp, hb_lds, acc_fe, tid);

  // ---- block reduction ----
  float v = acc_fe;
  #pragma unroll
  for (int off = 32; off; off >>= 1) v += __shfl_down(v, off);
  if (l == 0) red[wv] = v;
  __syncthreads();
  if (tid == 0) {
    float s = 0.f;
    #pragma unroll
    for (int i = 0; i < 16; ++i) s += red[i];
    partial[blockIdx.x] = s;
  }
}

__global__ void finish_reduce(const float* __restrict__ partial, float* __restrict__ out) {
  __shared__ float r[4];
  float v = partial[threadIdx.x];   // 256 threads
  #pragma unroll
  for (int off = 32; off; off >>= 1) v += __shfl_down(v, off);
  if ((threadIdx.x & 63) == 0) r[threadIdx.x >> 6] = v;
  __syncthreads();
  if (threadIdx.x == 0) out[0] = r[0] + r[1] + r[2] + r[3];
}

extern "C" void kernel_launch(void* const* d_in, const int* in_sizes, int n_in,
                              void* d_out, int out_size, void* d_ws, size_t ws_size,
                              hipStream_t stream) {
  const float* inputs = (const float*)d_in[0];
  const float* w      = (const float*)d_in[1];
  const float* vb     = (const float*)d_in[2];
  const float* hb     = (const float*)d_in[3];
  float* out = (float*)d_out;

  unsigned short* w_hi  = (unsigned short*)d_ws;                          // 512 KB
  unsigned short* w_lo  = (unsigned short*)((char*)d_ws + (512u << 10));  // 512 KB
  unsigned short* wt_hi = (unsigned short*)((char*)d_ws + (1024u << 10)); // 512 KB
  unsigned short* wt_lo = (unsigned short*)((char*)d_ws + (1536u << 10)); // 512 KB
  float* partial        = (float*)((char*)d_ws + (2048u << 10));          // 1 KB

  // ---- JAX threefry key schedule on host (pure arithmetic, capture-safe) ----
  TFKeys K;
  uint32_t kc0, kc1;
  tf2x32(0u, 42u, 0u, 0u, K.kh0_0, K.kh0_1);   // fold_in(key(42), 0)
  tf2x32(0u, 42u, 0u, 1u, kc0, kc1);           // fold_in(key(42), 1)
  // split(kchain, 10): counts = iota(20), cipher pairs (i, 10+i)
  uint32_t A[NSTEP], B[NSTEP], flat[2 * NSTEP];
  for (int i = 0; i < NSTEP; ++i) tf2x32(kc0, kc1, (uint32_t)i, (uint32_t)(NSTEP + i), A[i], B[i]);
  for (int i = 0; i < NSTEP; ++i) { flat[i] = A[i]; flat[NSTEP + i] = B[i]; }
  for (int t = 0; t < NSTEP; ++t) {
    uint32_t key0 = flat[2 * t], key1 = flat[2 * t + 1];
    // split(keys[t], 2): counts = iota(4), cipher pairs (0,2) and (1,3)
    uint32_t C0, D0, C1, D1;
    tf2x32(key0, key1, 0u, 2u, C0, D0);
    tf2x32(key0, key1, 1u, 3u, C1, D1);
    K.kv0[t] = C0; K.kv1[t] = C1;    // kv = first row of reshaped (2,2)
    K.khs0[t] = D0; K.khs1[t] = D1;  // kh = second row
  }

  prep_w<<<1024, 256, 0, stream>>>(w, w_hi, w_lo, wt_hi, wt_lo);
  rbm_chain<<<256, 1024, 0, stream>>>(inputs, vb, hb, w_hi, w_lo, wt_hi, wt_lo, partial, K);
  finish_reduce<<<1, 256, 0, stream>>>(partial, out);
}